// Round 4
// baseline (168.676 us; speedup 1.0000x reference)
//
#include <hip/hip_runtime.h>
#include <math.h>

#define NB 8
#define NL 4096
#define ND 2048
#define NE 8
#define KTOP 2
#define NR 8
#define ALPHA 0.125f
#define LN_EPS 1e-5f

#define GB 4                    // batches per group (128 MB of x -> fits L3 with slack)
#define NG (NB / GB)            // 2 groups
#define SPLIT_S 32              // L-chunks per batch in kA
#define ROWS_PER_S (NL / SPLIT_S)   // 128
#define DSL 8                   // 256-col d-slices

typedef float f32x4 __attribute__((ext_vector_type(4)));

// ---------------- kA: partial sums of x for group g -> partial[b_local][s][D]
// 1024 blocks: b_local(4) x s(32) x dsl(8). Normal loads: allocate x[g] in L3.
__global__ __launch_bounds__(256) void kA_partial(const float* __restrict__ x,
                                                  float* __restrict__ partial, int g) {
    int bid = blockIdx.x;
    int b_local = bid >> 8;             // /256
    int rem = bid & 255;
    int s = rem >> 3, dsl = rem & 7;
    int b = g * GB + b_local;
    int c4 = threadIdx.x & 63;          // float4 col within 256-col slice
    int rbase = threadIdx.x >> 6;       // 0..3
    const float* xp = x + ((size_t)(b * NL + s * ROWS_PER_S + rbase)) * ND
                        + dsl * 256 + c4 * 4;
    f32x4 acc = {0.f, 0.f, 0.f, 0.f};
#pragma unroll 8
    for (int i = 0; i < ROWS_PER_S / 4; ++i) {
        f32x4 v = *(const f32x4*)(xp + (size_t)(4 * i) * ND);
        acc += v;
    }
    __shared__ f32x4 lds[256];
    lds[threadIdx.x] = acc;
    __syncthreads();
    if (threadIdx.x < 64) {
        f32x4 r = lds[threadIdx.x] + lds[threadIdx.x + 64] +
                  lds[threadIdx.x + 128] + lds[threadIdx.x + 192];
        *(f32x4*)(partial + (size_t)(b_local * SPLIT_S + s) * ND + dsl * 256
                  + threadIdx.x * 4) = r;
    }
}

// ---------------- kB: reduce partial -> h, router, LoRA delta (1 block per b in group)
__global__ __launch_bounds__(256) void kB_router(const float* __restrict__ partial,
                                                 const float* __restrict__ gate_w,
                                                 const float* __restrict__ gate_b,
                                                 const float* __restrict__ A,
                                                 const float* __restrict__ Bw,
                                                 float* __restrict__ delta,
                                                 float* __restrict__ logits_out,
                                                 int* __restrict__ idx_out, int g) {
    __shared__ float sh_h[ND];
    __shared__ float sh_logits[NE];
    __shared__ float sh_t[KTOP * NR];
    __shared__ float sh_w[KTOP];
    __shared__ int sh_idx[KTOP];
    int b_local = blockIdx.x;
    int b = g * GB + b_local;
    int tid = threadIdx.x;

    // reduce the 32 s-partials -> h (fixed order: deterministic)
    for (int d4 = tid; d4 < ND / 4; d4 += 256) {
        f32x4 sum = {0.f, 0.f, 0.f, 0.f};
#pragma unroll
        for (int s = 0; s < SPLIT_S; ++s)
            sum += *(const f32x4*)(partial + (size_t)(b_local * SPLIT_S + s) * ND + d4 * 4);
        f32x4 r = sum * (1.0f / NL);
        *(f32x4*)(sh_h + d4 * 4) = r;
    }
    __syncthreads();

    // logits: 32 lanes per expert, float4 per lane
    {
        int e = tid >> 5, lane32 = tid & 31;
        const f32x4* gw = (const f32x4*)(gate_w + (size_t)e * ND);
        float p = 0.f;
#pragma unroll 4
        for (int d4 = lane32; d4 < ND / 4; d4 += 32) {
            f32x4 gv = gw[d4];
            f32x4 hv = *(const f32x4*)(sh_h + d4 * 4);
            p += gv.x * hv.x + gv.y * hv.y + gv.z * hv.z + gv.w * hv.w;
        }
        for (int off = 16; off; off >>= 1) p += __shfl_down(p, off);
        if (lane32 == 0) sh_logits[e] = p + gate_b[e];
    }
    __syncthreads();

    // top-2 + softmax weights (lane 0)
    if (tid == 0) {
        float v1 = -1e30f; int e1 = 0;
        for (int e = 0; e < NE; ++e) if (sh_logits[e] > v1) { v1 = sh_logits[e]; e1 = e; }
        float v2 = -1e30f; int e2 = 0;
        for (int e = 0; e < NE; ++e) if (e != e1 && sh_logits[e] > v2) { v2 = sh_logits[e]; e2 = e; }
        float ex = expf(v2 - v1);
        float w1 = 1.0f / (1.0f + ex);
        sh_idx[0] = e1; sh_idx[1] = e2;
        sh_w[0] = w1; sh_w[1] = ex * w1;
        idx_out[b * KTOP] = e1; idx_out[b * KTOP + 1] = e2;
        for (int e = 0; e < NE; ++e) logits_out[b * NE + e] = sh_logits[e];
    }
    __syncthreads();

    // t[k][r] = <h, A[e_k, r, :]> : 16-lane group per (k,r), float4 per lane
    {
        int grp = tid >> 4, lane16 = tid & 15;
        int k = grp >> 3, r = grp & 7;
        int e = sh_idx[k];
        const f32x4* ap = (const f32x4*)(A + ((size_t)e * NR + r) * ND);
        float p = 0.f;
#pragma unroll 4
        for (int d4 = lane16; d4 < ND / 4; d4 += 16) {
            f32x4 av = ap[d4];
            f32x4 hv = *(const f32x4*)(sh_h + d4 * 4);
            p += av.x * hv.x + av.y * hv.y + av.z * hv.z + av.w * hv.w;
        }
        for (int off = 8; off; off >>= 1) p += __shfl_down(p, off);
        if (lane16 == 0) sh_t[grp] = p;
    }
    __syncthreads();

    // delta[b,d] = alpha * sum_k w_k * sum_r t[k,r]*Bw[e_k,d,r]
    for (int dd = tid; dd < ND; dd += 256) {
        float acc = 0.f;
#pragma unroll
        for (int k = 0; k < KTOP; ++k) {
            int e = sh_idx[k];
            const f32x4* bw = (const f32x4*)(Bw + ((size_t)e * ND + dd) * NR);
            f32x4 w0 = bw[0], w1 = bw[1];
            float s = sh_t[k * NR + 0] * w0.x + sh_t[k * NR + 1] * w0.y +
                      sh_t[k * NR + 2] * w0.z + sh_t[k * NR + 3] * w0.w +
                      sh_t[k * NR + 4] * w1.x + sh_t[k * NR + 5] * w1.y +
                      sh_t[k * NR + 6] * w1.z + sh_t[k * NR + 7] * w1.w;
            acc += sh_w[k] * s;
        }
        delta[b * ND + dd] = acc * ALPHA;
    }
}

// ---------------- k3: aux losses (scalar)
__global__ void k3_aux(const float* __restrict__ logits, const int* __restrict__ idxp,
                       float* __restrict__ aux_out) {
    if (threadIdx.x != 0 || blockIdx.x != 0) return;
    float counts[NE];
    for (int e = 0; e < NE; ++e) counts[e] = 0.f;
    for (int i = 0; i < NB * KTOP; ++i) counts[idxp[i]] += 1.f;
    float f[NE], P[NE];
    for (int e = 0; e < NE; ++e) { f[e] = counts[e] * (1.0f / (NB * KTOP)); P[e] = 0.f; }
    float z = 0.f;
    for (int b = 0; b < NB; ++b) {
        const float* lg = logits + b * NE;
        float m = lg[0];
        for (int e = 1; e < NE; ++e) m = fmaxf(m, lg[e]);
        float s = 0.f;
        for (int e = 0; e < NE; ++e) s += expf(lg[e] - m);
        float inv = 1.0f / s;
        for (int e = 0; e < NE; ++e) P[e] += expf(lg[e] - m) * inv;
        float lse = m + logf(s);
        z += lse * lse;
    }
    z *= (1.0f / NB);
    float lb = 0.f;
    for (int e = 0; e < NE; ++e) lb += f[e] * (P[e] * (1.0f / NB));
    lb *= (float)NE;
    float psum = 0.f;
    for (int e = 0; e < NE; ++e) psum += f[e] + 1e-8f;
    float s2 = 0.f;
    for (int e = 0; e < NE; ++e) { float p = (f[e] + 1e-8f) / psum; s2 += p * p; }
    float renyi = logf(s2);
    aux_out[0] = 0.01f * lb + 0.001f * z + 0.01f * renyi;
}

// ---------------- kC: residual + LayerNorm for group g, one block per row.
// x[g] should be L3-resident from kA. y stores NON-TEMPORAL: don't evict x.
__global__ __launch_bounds__(256) void kC_ln(const float* __restrict__ x,
                                             const float* __restrict__ delta,
                                             const float* __restrict__ gamma,
                                             const float* __restrict__ beta,
                                             float* __restrict__ y, int g) {
    int b = g * GB + (blockIdx.x >> 12);       // blockIdx / NL
    size_t base = ((size_t)g * GB * NL + blockIdx.x) * ND;
    int tid = threadIdx.x;
    int d0 = tid * 8;

    float4 xa = *(const float4*)(x + base + d0);
    float4 xb = *(const float4*)(x + base + d0 + 4);
    float4 da = *(const float4*)(delta + (size_t)b * ND + d0);
    float4 db = *(const float4*)(delta + (size_t)b * ND + d0 + 4);
    float v[8] = {xa.x + da.x, xa.y + da.y, xa.z + da.z, xa.w + da.w,
                  xb.x + db.x, xb.y + db.y, xb.z + db.z, xb.w + db.w};
    float s = 0.f, ss = 0.f;
#pragma unroll
    for (int j = 0; j < 8; ++j) { s += v[j]; ss += v[j] * v[j]; }
    for (int off = 32; off; off >>= 1) { s += __shfl_down(s, off); ss += __shfl_down(ss, off); }

    __shared__ float red[2][4];
    __shared__ float stats[2];
    int wid = tid >> 6, lane = tid & 63;
    if (lane == 0) { red[0][wid] = s; red[1][wid] = ss; }
    __syncthreads();
    if (tid == 0) {
        float S = red[0][0] + red[0][1] + red[0][2] + red[0][3];
        float SS = red[1][0] + red[1][1] + red[1][2] + red[1][3];
        float mu = S * (1.0f / ND);
        float var = SS * (1.0f / ND) - mu * mu;
        stats[0] = mu;
        stats[1] = rsqrtf(var + LN_EPS);
    }
    __syncthreads();
    float mu = stats[0], rstd = stats[1];

    float4 ga = *(const float4*)(gamma + d0);
    float4 gb = *(const float4*)(gamma + d0 + 4);
    float4 ba = *(const float4*)(beta + d0);
    float4 bb = *(const float4*)(beta + d0 + 4);
    f32x4 oa, ob;
    oa.x = (v[0] - mu) * rstd * ga.x + ba.x;
    oa.y = (v[1] - mu) * rstd * ga.y + ba.y;
    oa.z = (v[2] - mu) * rstd * ga.z + ba.z;
    oa.w = (v[3] - mu) * rstd * ga.w + ba.w;
    ob.x = (v[4] - mu) * rstd * gb.x + bb.x;
    ob.y = (v[5] - mu) * rstd * gb.y + bb.y;
    ob.z = (v[6] - mu) * rstd * gb.z + bb.z;
    ob.w = (v[7] - mu) * rstd * gb.w + bb.w;
    __builtin_nontemporal_store(oa, (f32x4*)(y + base + d0));
    __builtin_nontemporal_store(ob, (f32x4*)(y + base + d0 + 4));
}

extern "C" void kernel_launch(void* const* d_in, const int* in_sizes, int n_in,
                              void* d_out, int out_size, void* d_ws, size_t ws_size,
                              hipStream_t stream) {
    const float* x      = (const float*)d_in[0];
    const float* gate_w = (const float*)d_in[1];
    const float* gate_b = (const float*)d_in[2];
    const float* A      = (const float*)d_in[3];
    const float* Bw     = (const float*)d_in[4];
    const float* gamma  = (const float*)d_in[5];
    const float* beta   = (const float*)d_in[6];
    float* y   = (float*)d_out;
    float* aux = y + (size_t)NB * NL * ND;

    // workspace: partial[GB][SPLIT_S][D] (reused per group) | delta[B][D] | logits[B][E] | idx[B][K]
    float* partial = (float*)d_ws;
    float* delta   = partial + (size_t)GB * SPLIT_S * ND;
    float* logits  = delta + NB * ND;
    int*   idxp    = (int*)(logits + NB * NE);

    for (int g = 0; g < NG; ++g) {
        hipLaunchKernelGGL(kA_partial, dim3(GB * SPLIT_S * DSL), dim3(256), 0, stream,
                           x, partial, g);
        hipLaunchKernelGGL(kB_router, dim3(GB), dim3(256), 0, stream,
                           partial, gate_w, gate_b, A, Bw, delta, logits, idxp, g);
        hipLaunchKernelGGL(kC_ln, dim3(GB * NL), dim3(256), 0, stream,
                           x, delta, gamma, beta, y, g);
    }
    hipLaunchKernelGGL(k3_aux, dim3(1), dim3(64), 0, stream, logits, idxp, aux);
}

// Round 5
// 151.900 us; speedup vs baseline: 1.1104x; 1.1104x over previous
//
#include <hip/hip_runtime.h>
#include <math.h>

#define NB 8
#define NL 4096
#define ND 2048
#define NE 8
#define KTOP 2
#define NR 8
#define ALPHA 0.125f
#define LN_EPS 1e-5f
#define SPLIT 64

typedef float f32x4 __attribute__((ext_vector_type(4)));

// ---------------- k1: partial sums of x over L chunks -> partial[b][s][D]
// grid: SPLIT * NB * 2 halves = 1024 blocks. 4 independent accumulators.
__global__ __launch_bounds__(256) void k1_partial_mean(const float* __restrict__ x,
                                                       float* __restrict__ partial) {
    int bid = blockIdx.x;
    int half = bid & 1;
    int b = (bid >> 1) & (NB - 1);
    int s = bid >> 4;
    const int lchunk = NL / SPLIT;     // 64
    int d4 = half * 1024 + threadIdx.x * 4;
    const float* xp = x + ((size_t)(b * NL + s * lchunk)) * ND + d4;
    f32x4 a0 = {0.f, 0.f, 0.f, 0.f}, a1 = a0, a2 = a0, a3 = a0;
    for (int i = 0; i < lchunk; i += 4) {
        f32x4 v0 = *(const f32x4*)(xp + (size_t)(i + 0) * ND);
        f32x4 v1 = *(const f32x4*)(xp + (size_t)(i + 1) * ND);
        f32x4 v2 = *(const f32x4*)(xp + (size_t)(i + 2) * ND);
        f32x4 v3 = *(const f32x4*)(xp + (size_t)(i + 3) * ND);
        a0 += v0; a1 += v1; a2 += v2; a3 += v3;
    }
    f32x4 acc = (a0 + a1) + (a2 + a3);
    *(f32x4*)(partial + ((size_t)(b * SPLIT + s)) * ND + d4) = acc;
}

// ---------------- kB: reduce partial -> h, router logits, top-2, LoRA delta.
// One block per b (8 blocks).
__global__ __launch_bounds__(256) void kB_router(const float* __restrict__ partial,
                                                 const float* __restrict__ gate_w,
                                                 const float* __restrict__ gate_b,
                                                 const float* __restrict__ A,
                                                 const float* __restrict__ Bw,
                                                 float* __restrict__ delta,
                                                 float* __restrict__ logits_out,
                                                 int* __restrict__ idx_out) {
    __shared__ float sh_h[ND];
    __shared__ float sh_logits[NE];
    __shared__ float sh_t[KTOP * NR];
    __shared__ float sh_w[KTOP];
    __shared__ int sh_idx[KTOP];
    int b = blockIdx.x;
    int tid = threadIdx.x;

    // reduce SPLIT partials -> h (contiguous [s][D] streams per b)
    const float* pb = partial + (size_t)b * SPLIT * ND;
    for (int d4 = tid; d4 < ND / 4; d4 += 256) {
        f32x4 s0 = {0.f, 0.f, 0.f, 0.f}, s1 = s0, s2 = s0, s3 = s0;
#pragma unroll 4
        for (int s = 0; s < SPLIT; s += 4) {
            s0 += *(const f32x4*)(pb + (size_t)(s + 0) * ND + d4 * 4);
            s1 += *(const f32x4*)(pb + (size_t)(s + 1) * ND + d4 * 4);
            s2 += *(const f32x4*)(pb + (size_t)(s + 2) * ND + d4 * 4);
            s3 += *(const f32x4*)(pb + (size_t)(s + 3) * ND + d4 * 4);
        }
        f32x4 r = ((s0 + s1) + (s2 + s3)) * (1.0f / NL);
        *(f32x4*)(sh_h + d4 * 4) = r;
    }
    __syncthreads();

    // logits: 32 lanes per expert, float4 per lane
    {
        int e = tid >> 5, lane32 = tid & 31;
        const f32x4* gw = (const f32x4*)(gate_w + (size_t)e * ND);
        float p = 0.f;
#pragma unroll 4
        for (int d4 = lane32; d4 < ND / 4; d4 += 32) {
            f32x4 gv = gw[d4];
            f32x4 hv = *(const f32x4*)(sh_h + d4 * 4);
            p += gv.x * hv.x + gv.y * hv.y + gv.z * hv.z + gv.w * hv.w;
        }
        for (int off = 16; off; off >>= 1) p += __shfl_down(p, off);
        if (lane32 == 0) sh_logits[e] = p + gate_b[e];
    }
    __syncthreads();

    // top-2 + softmax weights (lane 0)
    if (tid == 0) {
        float v1 = -1e30f; int e1 = 0;
        for (int e = 0; e < NE; ++e) if (sh_logits[e] > v1) { v1 = sh_logits[e]; e1 = e; }
        float v2 = -1e30f; int e2 = 0;
        for (int e = 0; e < NE; ++e) if (e != e1 && sh_logits[e] > v2) { v2 = sh_logits[e]; e2 = e; }
        float ex = expf(v2 - v1);
        float w1 = 1.0f / (1.0f + ex);
        sh_idx[0] = e1; sh_idx[1] = e2;
        sh_w[0] = w1; sh_w[1] = ex * w1;
        idx_out[b * KTOP] = e1; idx_out[b * KTOP + 1] = e2;
        for (int e = 0; e < NE; ++e) logits_out[b * NE + e] = sh_logits[e];
    }
    __syncthreads();

    // t[k][r] = <h, A[e_k, r, :]> : 16-lane group per (k,r)
    {
        int grp = tid >> 4, lane16 = tid & 15;
        int k = grp >> 3, r = grp & 7;
        int e = sh_idx[k];
        const f32x4* ap = (const f32x4*)(A + ((size_t)e * NR + r) * ND);
        float p = 0.f;
#pragma unroll 4
        for (int d4 = lane16; d4 < ND / 4; d4 += 16) {
            f32x4 av = ap[d4];
            f32x4 hv = *(const f32x4*)(sh_h + d4 * 4);
            p += av.x * hv.x + av.y * hv.y + av.z * hv.z + av.w * hv.w;
        }
        for (int off = 8; off; off >>= 1) p += __shfl_down(p, off);
        if (lane16 == 0) sh_t[grp] = p;
    }
    __syncthreads();

    // delta[b,d] = alpha * sum_k w_k * sum_r t[k,r]*Bw[e_k,d,r]
    for (int dd = tid; dd < ND; dd += 256) {
        float acc = 0.f;
#pragma unroll
        for (int k = 0; k < KTOP; ++k) {
            int e = sh_idx[k];
            const f32x4* bw = (const f32x4*)(Bw + ((size_t)e * ND + dd) * NR);
            f32x4 w0 = bw[0], w1 = bw[1];
            float s = sh_t[k * NR + 0] * w0.x + sh_t[k * NR + 1] * w0.y +
                      sh_t[k * NR + 2] * w0.z + sh_t[k * NR + 3] * w0.w +
                      sh_t[k * NR + 4] * w1.x + sh_t[k * NR + 5] * w1.y +
                      sh_t[k * NR + 6] * w1.z + sh_t[k * NR + 7] * w1.w;
            acc += sh_w[k] * s;
        }
        delta[b * ND + dd] = acc * ALPHA;
    }
}

// ---------------- k3: aux losses (scalar)
__global__ void k3_aux(const float* __restrict__ logits, const int* __restrict__ idxp,
                       float* __restrict__ aux_out) {
    if (threadIdx.x != 0 || blockIdx.x != 0) return;
    float counts[NE];
    for (int e = 0; e < NE; ++e) counts[e] = 0.f;
    for (int i = 0; i < NB * KTOP; ++i) counts[idxp[i]] += 1.f;
    float f[NE], P[NE];
    for (int e = 0; e < NE; ++e) { f[e] = counts[e] * (1.0f / (NB * KTOP)); P[e] = 0.f; }
    float z = 0.f;
    for (int b = 0; b < NB; ++b) {
        const float* lg = logits + b * NE;
        float m = lg[0];
        for (int e = 1; e < NE; ++e) m = fmaxf(m, lg[e]);
        float s = 0.f;
        for (int e = 0; e < NE; ++e) s += expf(lg[e] - m);
        float inv = 1.0f / s;
        for (int e = 0; e < NE; ++e) P[e] += expf(lg[e] - m) * inv;
        float lse = m + logf(s);
        z += lse * lse;
    }
    z *= (1.0f / NB);
    float lb = 0.f;
    for (int e = 0; e < NE; ++e) lb += f[e] * (P[e] * (1.0f / NB));
    lb *= (float)NE;
    float psum = 0.f;
    for (int e = 0; e < NE; ++e) psum += f[e] + 1e-8f;
    float s2 = 0.f;
    for (int e = 0; e < NE; ++e) { float p = (f[e] + 1e-8f) / psum; s2 += p * p; }
    float renyi = logf(s2);
    aux_out[0] = 0.01f * lb + 0.001f * z + 0.01f * renyi;
}

// ---------------- k4: residual + LayerNorm, ONE WAVE PER ROW (no barriers).
// 1024 blocks x 4 waves = 4096 waves; 32768 rows -> 8 rows/wave grid-stride.
// gamma/beta cached in registers across rows. y stores non-temporal.
__global__ __launch_bounds__(256) void k4_ln(const float* __restrict__ x,
                                             const float* __restrict__ delta,
                                             const float* __restrict__ gamma,
                                             const float* __restrict__ beta,
                                             float* __restrict__ y) {
    int wave = blockIdx.x * 4 + (threadIdx.x >> 6);   // global wave id, 0..4095
    int lane = threadIdx.x & 63;

    f32x4 g[8], be[8];
#pragma unroll
    for (int j = 0; j < 8; ++j) {
        g[j]  = *(const f32x4*)(gamma + (lane + 64 * j) * 4);
        be[j] = *(const f32x4*)(beta  + (lane + 64 * j) * 4);
    }

    for (int row = wave; row < NB * NL; row += 4096) {
        int b = row >> 12;
        const f32x4* xp = (const f32x4*)(x + (size_t)row * ND);
        const f32x4* dp = (const f32x4*)(delta + (size_t)b * ND);
        f32x4 v[8];
#pragma unroll
        for (int j = 0; j < 8; ++j) v[j] = xp[lane + 64 * j];
#pragma unroll
        for (int j = 0; j < 8; ++j) v[j] += dp[lane + 64 * j];

        float s = 0.f, ss = 0.f;
#pragma unroll
        for (int j = 0; j < 8; ++j) {
            s  += v[j].x + v[j].y + v[j].z + v[j].w;
            ss += v[j].x * v[j].x + v[j].y * v[j].y + v[j].z * v[j].z + v[j].w * v[j].w;
        }
        for (int off = 32; off; off >>= 1) {
            s  += __shfl_xor(s, off);
            ss += __shfl_xor(ss, off);
        }
        float mu = s * (1.0f / ND);
        float var = ss * (1.0f / ND) - mu * mu;
        float rstd = rsqrtf(var + LN_EPS);

        f32x4* yp = (f32x4*)(y + (size_t)row * ND);
#pragma unroll
        for (int j = 0; j < 8; ++j) {
            f32x4 o = (v[j] - mu) * rstd * g[j] + be[j];
            __builtin_nontemporal_store(o, yp + lane + 64 * j);
        }
    }
}

extern "C" void kernel_launch(void* const* d_in, const int* in_sizes, int n_in,
                              void* d_out, int out_size, void* d_ws, size_t ws_size,
                              hipStream_t stream) {
    const float* x      = (const float*)d_in[0];
    const float* gate_w = (const float*)d_in[1];
    const float* gate_b = (const float*)d_in[2];
    const float* A      = (const float*)d_in[3];
    const float* Bw     = (const float*)d_in[4];
    const float* gamma  = (const float*)d_in[5];
    const float* beta   = (const float*)d_in[6];
    float* y   = (float*)d_out;
    float* aux = y + (size_t)NB * NL * ND;

    // workspace: partial[B][SPLIT][D] | delta[B][D] | logits[B][E] | idx[B][K]
    float* partial = (float*)d_ws;
    float* delta   = partial + (size_t)NB * SPLIT * ND;
    float* logits  = delta + NB * ND;
    int*   idxp    = (int*)(logits + NB * NE);

    hipLaunchKernelGGL(k1_partial_mean, dim3(SPLIT * NB * 2), dim3(256), 0, stream,
                       x, partial);
    hipLaunchKernelGGL(kB_router, dim3(NB), dim3(256), 0, stream,
                       partial, gate_w, gate_b, A, Bw, delta, logits, idxp);
    hipLaunchKernelGGL(k3_aux, dim3(1), dim3(64), 0, stream, logits, idxp, aux);
    hipLaunchKernelGGL(k4_ln, dim3(1024), dim3(256), 0, stream,
                       x, delta, gamma, beta, y);
}